// Round 7
// baseline (320.855 us; speedup 1.0000x reference)
//
#include <hip/hip_runtime.h>
#include <hip/hip_bf16.h>

constexpr int NB = 32768;    // batch
constexpr int NF = 256;      // features
constexpr int NM = 10;       // memory slots
constexpr float DECAY = 0.9f;

using bf16x8 = __attribute__((ext_vector_type(8))) short;
using f32x4  = __attribute__((ext_vector_type(4))) float;

static __device__ __forceinline__ ushort f2bf(float x) {
    unsigned u = __float_as_uint(x);
    unsigned r = (u + 0x7fffu + ((u >> 16) & 1u)) >> 16;
    return (ushort)r;
}
static __device__ __forceinline__ float bf2f(ushort x) {
    return __uint_as_float(((unsigned)x) << 16);
}
static __device__ __forceinline__ float sigmoid_f(float x) {
    return 1.f / (1.f + __expf(-x));
}
static __device__ __forceinline__ float tanh_f(float x) {
    float e = __expf(2.f * x);
    return (e - 1.f) / (e + 1.f);
}
static __device__ __forceinline__ void gload16(const void* g, void* l) {
    __builtin_amdgcn_global_load_lds(
        (const __attribute__((address_space(1))) unsigned int*)g,
        (__attribute__((address_space(3))) unsigned int*)l, 16, 0, 0);
}

// ---------------- fused weight/input prep (one launch) ----------------
constexpr int PB_ACAT = 16384;
constexpr int PB_WGI  = PB_ACAT + 1024;
constexpr int PB_WQKT = PB_WGI + 256;
constexpr int PB_WV   = PB_WQKT + 256;
constexpr int PB_TOT  = PB_WV + 1;

__global__ __launch_bounds__(256) void k_prep(
    const float* __restrict__ W_ih, const float* __restrict__ W_hh,
    const float* __restrict__ b_ih, const float* __restrict__ b_hh,
    const float* __restrict__ Wq, const float* __restrict__ bq,
    const float* __restrict__ Wk, const float* __restrict__ Wv,
    const float* __restrict__ nf, const float* __restrict__ hidden,
    const int* __restrict__ idx,
    ushort* __restrict__ Wgi, float* __restrict__ bsum,
    ushort* __restrict__ WqkT, float* __restrict__ bqk,
    ushort* __restrict__ Wvb, ushort* __restrict__ Acat)
{
    const int blk = blockIdx.x, tid = threadIdx.x;
    if (blk < PB_ACAT) {
        int t = blk * 256 + tid;
        int row = t >> 7;
        int c4 = (t & 127) * 4;
        const float* src = (c4 < 256) ? (nf + (size_t)row * 256 + c4)
                                      : (hidden + (size_t)idx[row] * 256 + (c4 - 256));
        float4 v = *reinterpret_cast<const float4*>(src);
        ushort4 o;
        o.x = f2bf(v.x); o.y = f2bf(v.y); o.z = f2bf(v.z); o.w = f2bf(v.w);
        *reinterpret_cast<ushort4*>(Acat + (size_t)row * 512 + c4) = o;
    } else if (blk < PB_WGI) {
        int j = blk - PB_ACAT;
        int f = j >> 2, g = j & 3;
        int sr = g * 256 + f;
        for (int c = tid; c < 512; c += 256) {
            float v = (c < 256) ? W_ih[sr * 256 + c] : W_hh[sr * 256 + (c - 256)];
            Wgi[j * 512 + c] = f2bf(v);
        }
        if (tid == 0) bsum[j] = b_ih[sr] + b_hh[sr];
    } else if (blk < PB_WQKT) {
        int i = blk - PB_WGI, a = tid;
        float s = 0.f;
#pragma unroll 8
        for (int j = 0; j < 256; ++j) s += Wq[j * 256 + a] * Wk[j * 256 + i];
        WqkT[i * 256 + a] = f2bf(s * 0.0625f);
    } else if (blk < PB_WV) {
        int t = (blk - PB_WQKT) * 256 + tid;
        Wvb[t] = f2bf(Wv[t]);
    } else {
        int i = tid;
        float s = 0.f;
#pragma unroll 8
        for (int j = 0; j < 256; ++j) s += bq[j] * Wk[j * 256 + i];
        bqk[i] = s * 0.0625f;
    }
}

// ---------------- gates GEMM (128x128, BK=32) + fused LSTM (r4 form) ----------------
__global__ __launch_bounds__(256) void k_gates2(
    const ushort* __restrict__ Acat, const ushort* __restrict__ Wgi,
    const float* __restrict__ bsum, const int* __restrict__ idx,
    const float* __restrict__ cell, ushort* __restrict__ h_new)
{
    __shared__ ushort As[128 * 32];
    __shared__ ushort Bs[128 * 32];
    const int t = threadIdx.x;
    const int w = t >> 6, l = t & 63;
    const int wr = w >> 1, wc = w & 1;
    const int lr = l & 15, lk = l >> 4;
    const int row0 = blockIdx.x * 128;
    const int col0 = blockIdx.y * 128;

    f32x4 acc[4][4];
#pragma unroll
    for (int m = 0; m < 4; ++m)
#pragma unroll
        for (int n = 0; n < 4; ++n) acc[m][n] = f32x4{0.f, 0.f, 0.f, 0.f};

    const int srow = l >> 2;
    const int scol = (l & 3) * 8;
    const int u0 = w * 2, u1 = u0 + 1;
    const ushort* aS0 = Acat + (size_t)(row0 + u0 * 16 + srow) * 512 + scol;
    const ushort* aS1 = Acat + (size_t)(row0 + u1 * 16 + srow) * 512 + scol;
    const ushort* bS0 = Wgi  + (size_t)(col0 + u0 * 16 + srow) * 512 + scol;
    const ushort* bS1 = Wgi  + (size_t)(col0 + u1 * 16 + srow) * 512 + scol;
    ushort* aL0 = As + u0 * 512; ushort* aL1 = As + u1 * 512;
    ushort* bL0 = Bs + u0 * 512; ushort* bL1 = Bs + u1 * 512;

    for (int k0 = 0; k0 < 512; k0 += 32) {
        gload16(aS0 + k0, aL0);
        gload16(aS1 + k0, aL1);
        gload16(bS0 + k0, bL0);
        gload16(bS1 + k0, bL1);
        __syncthreads();
        bf16x8 af[4], bfr[4];
#pragma unroll
        for (int m = 0; m < 4; ++m)
            af[m] = *reinterpret_cast<const bf16x8*>(As + (wr * 64 + m * 16 + lr) * 32 + lk * 8);
#pragma unroll
        for (int n = 0; n < 4; ++n)
            bfr[n] = *reinterpret_cast<const bf16x8*>(Bs + (wc * 64 + n * 16 + lr) * 32 + lk * 8);
#pragma unroll
        for (int m = 0; m < 4; ++m)
#pragma unroll
            for (int n = 0; n < 4; ++n)
                acc[m][n] = __builtin_amdgcn_mfma_f32_16x16x32_bf16(af[m], bfr[n], acc[m][n], 0, 0, 0);
        __syncthreads();
    }

    float bb[4];
#pragma unroll
    for (int n = 0; n < 4; ++n) bb[n] = bsum[col0 + wc * 64 + n * 16 + lr];
#pragma unroll
    for (int m = 0; m < 4; ++m)
#pragma unroll
        for (int n = 0; n < 4; ++n)
#pragma unroll
            for (int r = 0; r < 4; ++r) acc[m][n][r] += bb[n];

    const int g0 = lr & 3;
    const int fq = lr >> 2;
    const bool is0 = (g0 == 0), is1 = (g0 == 1), is2 = (g0 == 2), is3 = (g0 == 3);
    const int fbase = (col0 >> 2) + wc * 16;

    int nodev[4];
#pragma unroll
    for (int r = 0; r < 4; ++r)
        nodev[r] = idx[row0 + wr * 64 + g0 * 16 + lk * 4 + r];

#pragma unroll
    for (int n = 0; n < 4; ++n) {
#pragma unroll
        for (int r = 0; r < 4; ++r) {
            float own = is0 ? acc[0][n][r] : is1 ? acc[1][n][r] : is2 ? acc[2][n][r] : acc[3][n][r];
            float s1  = is0 ? acc[1][n][r] : is1 ? acc[0][n][r] : is2 ? acc[3][n][r] : acc[2][n][r];
            float s2  = is0 ? acc[2][n][r] : is1 ? acc[3][n][r] : is2 ? acc[0][n][r] : acc[1][n][r];
            float s3  = is0 ? acc[3][n][r] : is1 ? acc[2][n][r] : is2 ? acc[1][n][r] : acc[0][n][r];
            float r1 = __shfl_xor(s1, 1, 64);
            float r2 = __shfl_xor(s2, 2, 64);
            float r3 = __shfl_xor(s3, 3, 64);
            float gi = is0 ? own : is1 ? r1 : is2 ? r2 : r3;
            float gf = is1 ? own : is0 ? r1 : is3 ? r2 : r3;
            float gg = is2 ? own : is3 ? r1 : is0 ? r2 : r3;
            float go = is3 ? own : is2 ? r1 : is1 ? r2 : r3;
            int fg = fbase + n * 4 + fq;
            float cp = cell[(size_t)nodev[r] * 256 + fg];
            float cn = sigmoid_f(gf) * cp + sigmoid_f(gi) * tanh_f(gg);
            float hn = sigmoid_f(go) * tanh_f(cn);
            int grow = row0 + wr * 64 + g0 * 16 + lk * 4 + r;
            h_new[(size_t)grow * 256 + fg] = f2bf(hn);
        }
    }
}

// ---------------- q GEMM: qbuf = hnew @ WqkT^T + bqk (bf16) ----------------
__global__ __launch_bounds__(256) void k_qk(
    const ushort* __restrict__ hnew, const ushort* __restrict__ WqkT,
    const float* __restrict__ bqk, ushort* __restrict__ qbuf)
{
    __shared__ ushort As[64 * 32];   // 4 KB
    const int t = threadIdx.x, w = t >> 6, l = t & 63;
    const int lr = l & 15, lk = l >> 4;
    const int row0 = blockIdx.x * 64;

    f32x4 acc[4][4];
#pragma unroll
    for (int m = 0; m < 4; ++m)
#pragma unroll
        for (int n = 0; n < 4; ++n) acc[m][n] = f32x4{0.f, 0.f, 0.f, 0.f};

    const int srow = w * 16 + (l >> 2);
    const int scol = (l & 3) * 8;
    const ushort* aS = hnew + (size_t)(row0 + srow) * 256 + scol;
    ushort* aL = As + (w * 16) * 32;

    const ushort* bptr[4];
#pragma unroll
    for (int n = 0; n < 4; ++n) bptr[n] = WqkT + (size_t)(w * 64 + n * 16 + lr) * 256 + lk * 8;

    for (int k0 = 0; k0 < 256; k0 += 32) {
        gload16(aS + k0, aL);
        __syncthreads();
        bf16x8 a[4], b[4];
#pragma unroll
        for (int m = 0; m < 4; ++m)
            a[m] = *reinterpret_cast<const bf16x8*>(As + (m * 16 + lr) * 32 + lk * 8);
#pragma unroll
        for (int n = 0; n < 4; ++n) b[n] = *reinterpret_cast<const bf16x8*>(bptr[n] + k0);
#pragma unroll
        for (int m = 0; m < 4; ++m)
#pragma unroll
            for (int n = 0; n < 4; ++n)
                acc[m][n] = __builtin_amdgcn_mfma_f32_16x16x32_bf16(a[m], b[n], acc[m][n], 0, 0, 0);
        __syncthreads();
    }

#pragma unroll
    for (int m = 0; m < 4; ++m)
#pragma unroll
        for (int n = 0; n < 4; ++n) {
            int colc = w * 64 + n * 16 + lr;
            float bbq = bqk[colc];
#pragma unroll
            for (int r = 0; r < 4; ++r) {
                int row = row0 + m * 16 + lk * 4 + r;
                qbuf[(size_t)row * 256 + colc] = f2bf(acc[m][n][r] + bbq);
            }
        }
}

// ---------------- attention + out GEMM (16 rows/block, grid NB/16) ----------------
static __device__ __forceinline__ int swzb(int row, int byteInRow) {
    return (row * 512 + byteInRow) ^ ((row & 7) << 4);
}

__global__ __launch_bounds__(256) void k_attnout(
    const ushort* __restrict__ qbuf, const ushort* __restrict__ Wvb,
    const float* __restrict__ bv, const int* __restrict__ idx,
    const int* __restrict__ mptr, const float* __restrict__ tm,
    const float* __restrict__ nf, float* __restrict__ out)
{
    __shared__ ushort sC[16 * 256];     // 8 KB: ctx rows (swizzled)
    char* sB = (char*)sC;
    const int t = threadIdx.x, w = t >> 6, l = t & 63;
    const int lr = l & 15, lk = l >> 4;
    const int row0 = blockIdx.x * 16;

    {
        const int b0 = row0 + w * 4;
        int nodes[4], ptrs[4];
#pragma unroll
        for (int r = 0; r < 4; ++r) { nodes[r] = idx[b0 + r]; ptrs[r] = mptr[nodes[r]]; }

#pragma unroll
        for (int rr = 0; rr < 4; ++rr) {
            int row = w * 4 + rr;
            int b = b0 + rr;
            int node = nodes[rr];
            int ptr = ptrs[rr];
            ushort4 q4 = *reinterpret_cast<const ushort4*>(qbuf + (size_t)b * 256 + l * 4);
            float q0 = bf2f(q4.x), q1 = bf2f(q4.y), q2 = bf2f(q4.z), q3 = bf2f(q4.w);
            const float* base = tm + (size_t)node * (NM * NF);

            float4 mem[NM];
            float sc[NM];
#pragma unroll
            for (int m = 0; m < NM; ++m) {
                float4 v;
                if (m == ptr) {
                    v = *reinterpret_cast<const float4*>(nf + (size_t)b * 256 + l * 4);
                } else {
                    v = *reinterpret_cast<const float4*>(base + (size_t)m * 256 + l * 4);
                    if (ptr > 0 && m == ptr - 1) { v.x *= DECAY; v.y *= DECAY; v.z *= DECAY; v.w *= DECAY; }
                }
                mem[m] = v;
                sc[m] = q0 * v.x + q1 * v.y + q2 * v.z + q3 * v.w;
            }
#pragma unroll
            for (int m = 0; m < NM; ++m) {
                float s = sc[m];
#pragma unroll
                for (int d = 1; d < 64; d <<= 1) s += __shfl_xor(s, d, 64);
                sc[m] = s;
            }
            float mx = sc[0];
#pragma unroll
            for (int m = 1; m < NM; ++m) mx = fmaxf(mx, sc[m]);
            float e[NM], sum = 0.f;
#pragma unroll
            for (int m = 0; m < NM; ++m) { e[m] = __expf(sc[m] - mx); sum += e[m]; }
            float inv = 1.f / sum;

            float4 c = {0.f, 0.f, 0.f, 0.f};
#pragma unroll
            for (int m = 0; m < NM; ++m) {
                float wm = e[m] * inv;
                c.x += wm * mem[m].x; c.y += wm * mem[m].y; c.z += wm * mem[m].z; c.w += wm * mem[m].w;
            }
            ushort4 o;
            o.x = f2bf(c.x); o.y = f2bf(c.y); o.z = f2bf(c.z); o.w = f2bf(c.w);
            *(ushort4*)(sB + swzb(row, l * 8)) = o;
        }
    }
    __syncthreads();

    f32x4 acc[4];
#pragma unroll
    for (int n = 0; n < 4; ++n) acc[n] = f32x4{0.f, 0.f, 0.f, 0.f};
    const ushort* vptr[4];
#pragma unroll
    for (int n = 0; n < 4; ++n) vptr[n] = Wvb + (size_t)(w * 64 + n * 16 + lr) * 256 + lk * 8;

#pragma unroll 2
    for (int k = 0; k < 256; k += 32) {
        bf16x8 a = *reinterpret_cast<const bf16x8*>(sB + swzb(lr, (k + lk * 8) * 2));
        bf16x8 b[4];
#pragma unroll
        for (int n = 0; n < 4; ++n) b[n] = *reinterpret_cast<const bf16x8*>(vptr[n] + k);
#pragma unroll
        for (int n = 0; n < 4; ++n)
            acc[n] = __builtin_amdgcn_mfma_f32_16x16x32_bf16(a, b[n], acc[n], 0, 0, 0);
    }
#pragma unroll
    for (int n = 0; n < 4; ++n) {
        int colc = w * 64 + n * 16 + lr;
        float bbv = bv[colc];
#pragma unroll
        for (int r = 0; r < 4; ++r) {
            int row = lk * 4 + r;
            out[(size_t)(row0 + row) * 256 + colc] = acc[n][r] + bbv;
        }
    }
}

// ---------------- launch ----------------
// MEASUREMENT ROUND: prep/gates/qk are idempotent (pure functions of inputs),
// each launched TWICE. dur7 - dur4 = P + G + Q + 3*gap, and
// attnout A = 2*dur4 - dur7 - gap. Deterministic: identical outputs each call.
extern "C" void kernel_launch(void* const* d_in, const int* in_sizes, int n_in,
                              void* d_out, int out_size, void* d_ws, size_t ws_size,
                              hipStream_t stream) {
    const int*   node_indices = (const int*)  d_in[0];
    const float* node_feats   = (const float*)d_in[1];
    const float* hidden       = (const float*)d_in[2];
    const float* cell         = (const float*)d_in[3];
    const float* tmem         = (const float*)d_in[4];
    const int*   memory_ptr   = (const int*)  d_in[5];
    const float* W_ih         = (const float*)d_in[6];
    const float* W_hh         = (const float*)d_in[7];
    const float* b_ih         = (const float*)d_in[8];
    const float* b_hh         = (const float*)d_in[9];
    const float* Wq           = (const float*)d_in[10];
    const float* bq           = (const float*)d_in[11];
    const float* Wk           = (const float*)d_in[12];
    // d_in[13] = bk: softmax-invariant, unused
    const float* Wv           = (const float*)d_in[14];
    const float* bv           = (const float*)d_in[15];

    char* ws = (char*)d_ws;
    size_t off = 0;
    auto alloc = [&](size_t bytes) { char* p = ws + off; off += (bytes + 255) & ~(size_t)255; return p; };

    ushort* Wgi   = (ushort*)alloc((size_t)1024 * 512 * 2);
    ushort* WqkT  = (ushort*)alloc((size_t)256 * 256 * 2);
    ushort* Wvb   = (ushort*)alloc((size_t)256 * 256 * 2);
    float*  bqk   = (float*) alloc((size_t)256 * 4);
    float*  bsum  = (float*) alloc((size_t)1024 * 4);
    ushort* Acat  = (ushort*)alloc((size_t)NB * 512 * 2);
    ushort* hnew  = (ushort*)alloc((size_t)NB * 256 * 2);
    ushort* qbuf  = (ushort*)alloc((size_t)NB * 256 * 2);

    k_prep<<<PB_TOT, 256, 0, stream>>>(W_ih, W_hh, b_ih, b_hh, Wq, bq, Wk, Wv,
                                       node_feats, hidden, node_indices,
                                       Wgi, bsum, WqkT, bqk, Wvb, Acat);
    k_prep<<<PB_TOT, 256, 0, stream>>>(W_ih, W_hh, b_ih, b_hh, Wq, bq, Wk, Wv,
                                       node_feats, hidden, node_indices,
                                       Wgi, bsum, WqkT, bqk, Wvb, Acat);
    k_gates2<<<dim3(NB / 128, 8), 256, 0, stream>>>(Acat, Wgi, bsum, node_indices, cell, hnew);
    k_gates2<<<dim3(NB / 128, 8), 256, 0, stream>>>(Acat, Wgi, bsum, node_indices, cell, hnew);
    k_qk<<<NB / 64, 256, 0, stream>>>(hnew, WqkT, bqk, qbuf);
    k_qk<<<NB / 64, 256, 0, stream>>>(hnew, WqkT, bqk, qbuf);
    k_attnout<<<NB / 16, 256, 0, stream>>>(qbuf, Wvb, bv, node_indices, memory_ptr,
                                           tmem, node_feats, (float*)d_out);
}

// Round 8
// 234.318 us; speedup vs baseline: 1.3693x; 1.3693x over previous
//
#include <hip/hip_runtime.h>
#include <hip/hip_bf16.h>

constexpr int NB = 32768;    // batch
constexpr int NF = 256;      // features
constexpr int NM = 10;       // memory slots
constexpr float DECAY = 0.9f;

using bf16x8 = __attribute__((ext_vector_type(8))) short;
using f32x4  = __attribute__((ext_vector_type(4))) float;

static __device__ __forceinline__ ushort f2bf(float x) {
    unsigned u = __float_as_uint(x);
    unsigned r = (u + 0x7fffu + ((u >> 16) & 1u)) >> 16;
    return (ushort)r;
}
static __device__ __forceinline__ float bf2f(ushort x) {
    return __uint_as_float(((unsigned)x) << 16);
}
static __device__ __forceinline__ float sigmoid_f(float x) {
    return 1.f / (1.f + __expf(-x));
}
static __device__ __forceinline__ float tanh_f(float x) {
    float e = __expf(2.f * x);
    return (e - 1.f) / (e + 1.f);
}
static __device__ __forceinline__ void gload16(const void* g, void* l) {
    __builtin_amdgcn_global_load_lds(
        (const __attribute__((address_space(1))) unsigned int*)g,
        (__attribute__((address_space(3))) unsigned int*)l, 16, 0, 0);
}

// ---------------- fused weight/input prep (one launch) ----------------
constexpr int PB_ACAT = 16384;
constexpr int PB_WGI  = PB_ACAT + 1024;
constexpr int PB_WQKT = PB_WGI + 256;
constexpr int PB_WV   = PB_WQKT + 256;
constexpr int PB_TOT  = PB_WV + 1;

__global__ __launch_bounds__(256) void k_prep(
    const float* __restrict__ W_ih, const float* __restrict__ W_hh,
    const float* __restrict__ b_ih, const float* __restrict__ b_hh,
    const float* __restrict__ Wq, const float* __restrict__ bq,
    const float* __restrict__ Wk, const float* __restrict__ Wv,
    const float* __restrict__ nf, const float* __restrict__ hidden,
    const int* __restrict__ idx,
    ushort* __restrict__ Wg, float* __restrict__ bsum,
    ushort* __restrict__ WqkT, float* __restrict__ bqk,
    ushort* __restrict__ Wvb, ushort* __restrict__ Acat)
{
    const int blk = blockIdx.x, tid = threadIdx.x;
    if (blk < PB_ACAT) {
        int t = blk * 256 + tid;
        int row = t >> 7;
        int c4 = (t & 127) * 4;
        const float* src = (c4 < 256) ? (nf + (size_t)row * 256 + c4)
                                      : (hidden + (size_t)idx[row] * 256 + (c4 - 256));
        float4 v = *reinterpret_cast<const float4*>(src);
        ushort4 o;
        o.x = f2bf(v.x); o.y = f2bf(v.y); o.z = f2bf(v.z); o.w = f2bf(v.w);
        *reinterpret_cast<ushort4*>(Acat + (size_t)row * 512 + c4) = o;
    } else if (blk < PB_WGI) {
        // Wg bf16 [1024][512], ORIGINAL row order j = g*256+f:
        // cols 0..255 = W_ih[j], 256..511 = W_hh[j]
        int j = blk - PB_ACAT;
        for (int c = tid; c < 512; c += 256) {
            float v = (c < 256) ? W_ih[j * 256 + c] : W_hh[j * 256 + (c - 256)];
            Wg[j * 512 + c] = f2bf(v);
        }
        if (tid == 0) bsum[j] = b_ih[j] + b_hh[j];
    } else if (blk < PB_WQKT) {
        int i = blk - PB_WGI, a = tid;
        float s = 0.f;
#pragma unroll 8
        for (int j = 0; j < 256; ++j) s += Wq[j * 256 + a] * Wk[j * 256 + i];
        WqkT[i * 256 + a] = f2bf(s * 0.0625f);
    } else if (blk < PB_WV) {
        int t = (blk - PB_WQKT) * 256 + tid;
        Wvb[t] = f2bf(Wv[t]);
    } else {
        int i = tid;
        float s = 0.f;
#pragma unroll 8
        for (int j = 0; j < 256; ++j) s += bq[j] * Wk[j * 256 + i];
        bqk[i] = s * 0.0625f;
    }
}

// ---------------- gates GEMM (128 rows x [32 feats x 4 gates]) + fused LSTM ----------------
// Gate-planar fragments: wave's 4 B-frags come from the 4 gate regions of Wg, so each
// lane ends with all 4 gates of one (row, feature) in acc[m][0..3][r]:
// NO gate shuffles; cell loads / h_new stores coalesced.
__global__ __launch_bounds__(256) void k_gates2(
    const ushort* __restrict__ Acat, const ushort* __restrict__ Wg,
    const float* __restrict__ bsum, const int* __restrict__ idx,
    const float* __restrict__ cell, ushort* __restrict__ h_new)
{
    __shared__ ushort As[128 * 32];      // A tile: 128 batch rows x 32 k
    __shared__ ushort Bs[128 * 32];      // B tile: rows g*32+i (gate g, feature i) x 32 k
    const int t = threadIdx.x;
    const int w = t >> 6, l = t & 63;
    const int wr = w >> 1, wc = w & 1;
    const int lr = l & 15, lk = l >> 4;
    const int row0 = blockIdx.x * 128;
    const int f0 = blockIdx.y * 32;      // feature block [f0, f0+32)

    f32x4 acc[4][4];                     // [m][gate]
#pragma unroll
    for (int m = 0; m < 4; ++m)
#pragma unroll
        for (int g = 0; g < 4; ++g) acc[m][g] = f32x4{0.f, 0.f, 0.f, 0.f};

    const int srow = l >> 2;
    const int scol = (l & 3) * 8;
    const int u0 = w * 2, u1 = u0 + 1;
    // A staging: chunk u covers tile rows [u*16, u*16+16)
    const ushort* aS0 = Acat + (size_t)(row0 + u0 * 16 + srow) * 512 + scol;
    const ushort* aS1 = Acat + (size_t)(row0 + u1 * 16 + srow) * 512 + scol;
    // B staging: wave w stages gate g=w, halves 0/1: Wg rows w*256 + f0 + {0,16} + srow
    const ushort* bS0 = Wg + (size_t)(w * 256 + f0 + srow) * 512 + scol;
    const ushort* bS1 = Wg + (size_t)(w * 256 + f0 + 16 + srow) * 512 + scol;
    ushort* aL0 = As + u0 * 512; ushort* aL1 = As + u1 * 512;
    ushort* bL0 = Bs + (w * 32) * 32; ushort* bL1 = Bs + (w * 32 + 16) * 32;

    for (int k0 = 0; k0 < 512; k0 += 32) {
        gload16(aS0 + k0, aL0);
        gload16(aS1 + k0, aL1);
        gload16(bS0 + k0, bL0);
        gload16(bS1 + k0, bL1);
        __syncthreads();
        bf16x8 af[4], bfr[4];
#pragma unroll
        for (int m = 0; m < 4; ++m)
            af[m] = *reinterpret_cast<const bf16x8*>(As + (wr * 64 + m * 16 + lr) * 32 + lk * 8);
#pragma unroll
        for (int g = 0; g < 4; ++g)
            bfr[g] = *reinterpret_cast<const bf16x8*>(Bs + (g * 32 + wc * 16 + lr) * 32 + lk * 8);
#pragma unroll
        for (int m = 0; m < 4; ++m)
#pragma unroll
            for (int g = 0; g < 4; ++g)
                acc[m][g] = __builtin_amdgcn_mfma_f32_16x16x32_bf16(af[m], bfr[g], acc[m][g], 0, 0, 0);
        __syncthreads();
    }

    // ---- epilogue: per lane, feature f fixed; all 4 gates local ----
    const int f = f0 + wc * 16 + lr;
    float bs[4];
#pragma unroll
    for (int g = 0; g < 4; ++g) bs[g] = bsum[g * 256 + f];

    int nodev[4][4];
#pragma unroll
    for (int m = 0; m < 4; ++m)
#pragma unroll
        for (int r = 0; r < 4; ++r)
            nodev[m][r] = idx[row0 + wr * 64 + m * 16 + lk * 4 + r];

#pragma unroll
    for (int m = 0; m < 4; ++m) {
#pragma unroll
        for (int r = 0; r < 4; ++r) {
            float gi = acc[m][0][r] + bs[0];
            float gf = acc[m][1][r] + bs[1];
            float gg = acc[m][2][r] + bs[2];
            float go = acc[m][3][r] + bs[3];
            float cp = cell[(size_t)nodev[m][r] * 256 + f];
            float cn = sigmoid_f(gf) * cp + sigmoid_f(gi) * tanh_f(gg);
            float hn = sigmoid_f(go) * tanh_f(cn);
            int row = row0 + wr * 64 + m * 16 + lk * 4 + r;
            h_new[(size_t)row * 256 + f] = f2bf(hn);
        }
    }
}

// ---------------- q GEMM: qbuf = hnew @ WqkT^T + bqk (bf16) ----------------
__global__ __launch_bounds__(256) void k_qk(
    const ushort* __restrict__ hnew, const ushort* __restrict__ WqkT,
    const float* __restrict__ bqk, ushort* __restrict__ qbuf)
{
    __shared__ ushort As[64 * 32];   // 4 KB
    const int t = threadIdx.x, w = t >> 6, l = t & 63;
    const int lr = l & 15, lk = l >> 4;
    const int row0 = blockIdx.x * 64;

    f32x4 acc[4][4];
#pragma unroll
    for (int m = 0; m < 4; ++m)
#pragma unroll
        for (int n = 0; n < 4; ++n) acc[m][n] = f32x4{0.f, 0.f, 0.f, 0.f};

    const int srow = w * 16 + (l >> 2);
    const int scol = (l & 3) * 8;
    const ushort* aS = hnew + (size_t)(row0 + srow) * 256 + scol;
    ushort* aL = As + (w * 16) * 32;

    const ushort* bptr[4];
#pragma unroll
    for (int n = 0; n < 4; ++n) bptr[n] = WqkT + (size_t)(w * 64 + n * 16 + lr) * 256 + lk * 8;

    for (int k0 = 0; k0 < 256; k0 += 32) {
        gload16(aS + k0, aL);
        __syncthreads();
        bf16x8 a[4], b[4];
#pragma unroll
        for (int m = 0; m < 4; ++m)
            a[m] = *reinterpret_cast<const bf16x8*>(As + (m * 16 + lr) * 32 + lk * 8);
#pragma unroll
        for (int n = 0; n < 4; ++n) b[n] = *reinterpret_cast<const bf16x8*>(bptr[n] + k0);
#pragma unroll
        for (int m = 0; m < 4; ++m)
#pragma unroll
            for (int n = 0; n < 4; ++n)
                acc[m][n] = __builtin_amdgcn_mfma_f32_16x16x32_bf16(a[m], b[n], acc[m][n], 0, 0, 0);
        __syncthreads();
    }

#pragma unroll
    for (int m = 0; m < 4; ++m)
#pragma unroll
        for (int n = 0; n < 4; ++n) {
            int colc = w * 64 + n * 16 + lr;
            float bbq = bqk[colc];
#pragma unroll
            for (int r = 0; r < 4; ++r) {
                int row = row0 + m * 16 + lk * 4 + r;
                qbuf[(size_t)row * 256 + colc] = f2bf(acc[m][n][r] + bbq);
            }
        }
}

// ---------------- attention + out GEMM (8 rows/block, grid NB/8) ----------------
static __device__ __forceinline__ int swzb(int row, int byteInRow) {
    return (row * 512 + byteInRow) ^ ((row & 7) << 4);
}

__global__ __launch_bounds__(256) void k_attnout(
    const ushort* __restrict__ qbuf, const ushort* __restrict__ Wvb,
    const float* __restrict__ bv, const int* __restrict__ idx,
    const int* __restrict__ mptr, const float* __restrict__ tm,
    const float* __restrict__ nf, float* __restrict__ out)
{
    __shared__ ushort sC[16 * 256];     // 8 KB; rows 0..7 = ctx, rows 8..15 unused (MFMA pad)
    char* sB = (char*)sC;
    const int t = threadIdx.x, w = t >> 6, l = t & 63;
    const int lr = l & 15, lk = l >> 4;
    const int row0 = blockIdx.x * 8;

    // ---- attention; wave w owns local rows [w*2, w*2+2); q read per-lane from global ----
    {
        const int b0 = row0 + w * 2;
        int nodes[2], ptrs[2];
#pragma unroll
        for (int r = 0; r < 2; ++r) { nodes[r] = idx[b0 + r]; ptrs[r] = mptr[nodes[r]]; }

#pragma unroll
        for (int rr = 0; rr < 2; ++rr) {
            int row = w * 2 + rr;
            int b = b0 + rr;
            int node = nodes[rr];
            int ptr = ptrs[rr];
            ushort4 q4 = *reinterpret_cast<const ushort4*>(qbuf + (size_t)b * 256 + l * 4);
            float q0 = bf2f(q4.x), q1 = bf2f(q4.y), q2 = bf2f(q4.z), q3 = bf2f(q4.w);
            const float* base = tm + (size_t)node * (NM * NF);

            float4 mem[NM];
            float sc[NM];
#pragma unroll
            for (int m = 0; m < NM; ++m) {
                float4 v;
                if (m == ptr) {
                    v = *reinterpret_cast<const float4*>(nf + (size_t)b * 256 + l * 4);
                } else {
                    v = *reinterpret_cast<const float4*>(base + (size_t)m * 256 + l * 4);
                    if (ptr > 0 && m == ptr - 1) { v.x *= DECAY; v.y *= DECAY; v.z *= DECAY; v.w *= DECAY; }
                }
                mem[m] = v;
                sc[m] = q0 * v.x + q1 * v.y + q2 * v.z + q3 * v.w;
            }
#pragma unroll
            for (int m = 0; m < NM; ++m) {
                float s = sc[m];
#pragma unroll
                for (int d = 1; d < 64; d <<= 1) s += __shfl_xor(s, d, 64);
                sc[m] = s;
            }
            float mx = sc[0];
#pragma unroll
            for (int m = 1; m < NM; ++m) mx = fmaxf(mx, sc[m]);
            float e[NM], sum = 0.f;
#pragma unroll
            for (int m = 0; m < NM; ++m) { e[m] = __expf(sc[m] - mx); sum += e[m]; }
            float inv = 1.f / sum;

            float4 c = {0.f, 0.f, 0.f, 0.f};
#pragma unroll
            for (int m = 0; m < NM; ++m) {
                float wm = e[m] * inv;
                c.x += wm * mem[m].x; c.y += wm * mem[m].y; c.z += wm * mem[m].z; c.w += wm * mem[m].w;
            }
            ushort4 o;
            o.x = f2bf(c.x); o.y = f2bf(c.y); o.z = f2bf(c.z); o.w = f2bf(c.w);
            *(ushort4*)(sB + swzb(row, l * 8)) = o;
        }
    }
    __syncthreads();

    // ---- out GEMM: out = ctx @ Wv^T + bv; 8 valid rows (MFMA rows 8..15 discarded) ----
    f32x4 acc[4];
#pragma unroll
    for (int n = 0; n < 4; ++n) acc[n] = f32x4{0.f, 0.f, 0.f, 0.f};
    const ushort* vptr[4];
#pragma unroll
    for (int n = 0; n < 4; ++n) vptr[n] = Wvb + (size_t)(w * 64 + n * 16 + lr) * 256 + lk * 8;

#pragma unroll 2
    for (int k = 0; k < 256; k += 32) {
        bf16x8 a = *reinterpret_cast<const bf16x8*>(sB + swzb(lr, (k + lk * 8) * 2));
        bf16x8 b[4];
#pragma unroll
        for (int n = 0; n < 4; ++n) b[n] = *reinterpret_cast<const bf16x8*>(vptr[n] + k);
#pragma unroll
        for (int n = 0; n < 4; ++n)
            acc[n] = __builtin_amdgcn_mfma_f32_16x16x32_bf16(a, b[n], acc[n], 0, 0, 0);
    }
    if (lk < 2) {
#pragma unroll
        for (int n = 0; n < 4; ++n) {
            int colc = w * 64 + n * 16 + lr;
            float bbv = bv[colc];
#pragma unroll
            for (int r = 0; r < 4; ++r) {
                int row = lk * 4 + r;
                out[(size_t)(row0 + row) * 256 + colc] = acc[n][r] + bbv;
            }
        }
    }
}

// ---------------- launch ----------------
extern "C" void kernel_launch(void* const* d_in, const int* in_sizes, int n_in,
                              void* d_out, int out_size, void* d_ws, size_t ws_size,
                              hipStream_t stream) {
    const int*   node_indices = (const int*)  d_in[0];
    const float* node_feats   = (const float*)d_in[1];
    const float* hidden       = (const float*)d_in[2];
    const float* cell         = (const float*)d_in[3];
    const float* tmem         = (const float*)d_in[4];
    const int*   memory_ptr   = (const int*)  d_in[5];
    const float* W_ih         = (const float*)d_in[6];
    const float* W_hh         = (const float*)d_in[7];
    const float* b_ih         = (const float*)d_in[8];
    const float* b_hh         = (const float*)d_in[9];
    const float* Wq           = (const float*)d_in[10];
    const float* bq           = (const float*)d_in[11];
    const float* Wk           = (const float*)d_in[12];
    // d_in[13] = bk: softmax-invariant, unused
    const float* Wv           = (const float*)d_in[14];
    const float* bv           = (const float*)d_in[15];

    char* ws = (char*)d_ws;
    size_t off = 0;
    auto alloc = [&](size_t bytes) { char* p = ws + off; off += (bytes + 255) & ~(size_t)255; return p; };

    ushort* Wg    = (ushort*)alloc((size_t)1024 * 512 * 2);
    ushort* WqkT  = (ushort*)alloc((size_t)256 * 256 * 2);
    ushort* Wvb   = (ushort*)alloc((size_t)256 * 256 * 2);
    float*  bqk   = (float*) alloc((size_t)256 * 4);
    float*  bsum  = (float*) alloc((size_t)1024 * 4);
    ushort* Acat  = (ushort*)alloc((size_t)NB * 512 * 2);
    ushort* hnew  = (ushort*)alloc((size_t)NB * 256 * 2);
    ushort* qbuf  = (ushort*)alloc((size_t)NB * 256 * 2);

    k_prep<<<PB_TOT, 256, 0, stream>>>(W_ih, W_hh, b_ih, b_hh, Wq, bq, Wk, Wv,
                                       node_feats, hidden, node_indices,
                                       Wg, bsum, WqkT, bqk, Wvb, Acat);
    k_gates2<<<dim3(NB / 128, 8), 256, 0, stream>>>(Acat, Wg, bsum, node_indices, cell, hnew);
    k_qk<<<NB / 64, 256, 0, stream>>>(hnew, WqkT, bqk, qbuf);
    k_attnout<<<NB / 8, 256, 0, stream>>>(qbuf, Wvb, bv, node_indices, memory_ptr,
                                          tmem, node_feats, (float*)d_out);
}

// Round 9
// 216.528 us; speedup vs baseline: 1.4818x; 1.0822x over previous
//
#include <hip/hip_runtime.h>
#include <hip/hip_bf16.h>

constexpr int NB = 32768;    // batch
constexpr int NF = 256;      // features
constexpr int NM = 10;       // memory slots
constexpr float DECAY = 0.9f;

using bf16x8 = __attribute__((ext_vector_type(8))) short;
using f32x4  = __attribute__((ext_vector_type(4))) float;

static __device__ __forceinline__ ushort f2bf(float x) {
    unsigned u = __float_as_uint(x);
    unsigned r = (u + 0x7fffu + ((u >> 16) & 1u)) >> 16;
    return (ushort)r;
}
static __device__ __forceinline__ float bf2f(ushort x) {
    return __uint_as_float(((unsigned)x) << 16);
}
static __device__ __forceinline__ float sigmoid_f(float x) {
    return 1.f / (1.f + __expf(-x));
}
static __device__ __forceinline__ float tanh_f(float x) {
    float e = __expf(2.f * x);
    return (e - 1.f) / (e + 1.f);
}
static __device__ __forceinline__ void gload16(const void* g, void* l) {
    __builtin_amdgcn_global_load_lds(
        (const __attribute__((address_space(1))) unsigned int*)g,
        (__attribute__((address_space(3))) unsigned int*)l, 16, 0, 0);
}

// ---------------- fused weight/input prep (one launch) ----------------
constexpr int PB_ACAT = 16384;
constexpr int PB_WGI  = PB_ACAT + 1024;
constexpr int PB_WQKT = PB_WGI + 256;
constexpr int PB_WV   = PB_WQKT + 256;
constexpr int PB_TOT  = PB_WV + 1;

__global__ __launch_bounds__(256) void k_prep(
    const float* __restrict__ W_ih, const float* __restrict__ W_hh,
    const float* __restrict__ b_ih, const float* __restrict__ b_hh,
    const float* __restrict__ Wq, const float* __restrict__ bq,
    const float* __restrict__ Wk, const float* __restrict__ Wv,
    const float* __restrict__ nf, const float* __restrict__ hidden,
    const int* __restrict__ idx,
    ushort* __restrict__ Wg, float* __restrict__ bsum,
    ushort* __restrict__ WqkT, float* __restrict__ bqk,
    ushort* __restrict__ Wvb, ushort* __restrict__ Acat)
{
    const int blk = blockIdx.x, tid = threadIdx.x;
    if (blk < PB_ACAT) {
        int t = blk * 256 + tid;
        int row = t >> 7;
        int c4 = (t & 127) * 4;
        const float* src = (c4 < 256) ? (nf + (size_t)row * 256 + c4)
                                      : (hidden + (size_t)idx[row] * 256 + (c4 - 256));
        float4 v = *reinterpret_cast<const float4*>(src);
        ushort4 o;
        o.x = f2bf(v.x); o.y = f2bf(v.y); o.z = f2bf(v.z); o.w = f2bf(v.w);
        *reinterpret_cast<ushort4*>(Acat + (size_t)row * 512 + c4) = o;
    } else if (blk < PB_WGI) {
        // Wg bf16 [1024][512], row j = g*256+f: cols 0..255 = W_ih[j], 256..511 = W_hh[j]
        int j = blk - PB_ACAT;
        for (int c = tid; c < 512; c += 256) {
            float v = (c < 256) ? W_ih[j * 256 + c] : W_hh[j * 256 + (c - 256)];
            Wg[j * 512 + c] = f2bf(v);
        }
        if (tid == 0) bsum[j] = b_ih[j] + b_hh[j];
    } else if (blk < PB_WQKT) {
        int i = blk - PB_WGI, a = tid;
        float s = 0.f;
#pragma unroll 8
        for (int j = 0; j < 256; ++j) s += Wq[j * 256 + a] * Wk[j * 256 + i];
        WqkT[i * 256 + a] = f2bf(s * 0.0625f);
    } else if (blk < PB_WV) {
        int t = (blk - PB_WQKT) * 256 + tid;
        Wvb[t] = f2bf(Wv[t]);
    } else {
        int i = tid;
        float s = 0.f;
#pragma unroll 8
        for (int j = 0; j < 256; ++j) s += bq[j] * Wk[j * 256 + i];
        bqk[i] = s * 0.0625f;
    }
}

// ---------------- gates GEMM (128 rows x [32 feats x 4 gates]) + fused LSTM ----------------
// Gate-planar B fragments: each lane ends with all 4 gates of one (row, feature) in
// acc[m][0..3][r] -> no gate shuffles; cell loads / h_new stores coalesced.
// Grid: FLAT 2048 blocks with XCD-cohort remap: the 8 feature-blocks (by) of one
// row-block (bx) share flat%8 (same XCD) and are dispatch-adjacent -> the 128 KB
// Acat A-panel is fetched from HBM once per bx (L2-shared), not 8x across XCDs.
__global__ __launch_bounds__(256) void k_gates2(
    const ushort* __restrict__ Acat, const ushort* __restrict__ Wg,
    const float* __restrict__ bsum, const int* __restrict__ idx,
    const float* __restrict__ cell, ushort* __restrict__ h_new)
{
    __shared__ ushort As[128 * 32];      // A tile: 128 batch rows x 32 k
    __shared__ ushort Bs[128 * 32];      // B tile: rows g*32+i (gate g, feature i) x 32 k
    const int t = threadIdx.x;
    const int w = t >> 6, l = t & 63;
    const int wr = w >> 1, wc = w & 1;
    const int lr = l & 15, lk = l >> 4;

    // XCD-cohort remap (8 XCDs, round-robin by flat%8)
    const int flat = blockIdx.x;
    const int xc = flat & 7, grp = flat >> 3;
    const int by = grp & 7;
    const int bx = (grp >> 3) * 8 + xc;
    const int row0 = bx * 128;
    const int f0 = by * 32;              // feature block [f0, f0+32)

    f32x4 acc[4][4];                     // [m][gate]
#pragma unroll
    for (int m = 0; m < 4; ++m)
#pragma unroll
        for (int g = 0; g < 4; ++g) acc[m][g] = f32x4{0.f, 0.f, 0.f, 0.f};

    const int srow = l >> 2;
    const int scol = (l & 3) * 8;
    const int u0 = w * 2, u1 = u0 + 1;
    const ushort* aS0 = Acat + (size_t)(row0 + u0 * 16 + srow) * 512 + scol;
    const ushort* aS1 = Acat + (size_t)(row0 + u1 * 16 + srow) * 512 + scol;
    // B staging: wave w stages gate g=w, halves 0/1: Wg rows w*256 + f0 + {0,16} + srow
    const ushort* bS0 = Wg + (size_t)(w * 256 + f0 + srow) * 512 + scol;
    const ushort* bS1 = Wg + (size_t)(w * 256 + f0 + 16 + srow) * 512 + scol;
    ushort* aL0 = As + u0 * 512; ushort* aL1 = As + u1 * 512;
    ushort* bL0 = Bs + (w * 32) * 32; ushort* bL1 = Bs + (w * 32 + 16) * 32;

    for (int k0 = 0; k0 < 512; k0 += 32) {
        gload16(aS0 + k0, aL0);
        gload16(aS1 + k0, aL1);
        gload16(bS0 + k0, bL0);
        gload16(bS1 + k0, bL1);
        __syncthreads();
        bf16x8 af[4], bfr[4];
#pragma unroll
        for (int m = 0; m < 4; ++m)
            af[m] = *reinterpret_cast<const bf16x8*>(As + (wr * 64 + m * 16 + lr) * 32 + lk * 8);
#pragma unroll
        for (int g = 0; g < 4; ++g)
            bfr[g] = *reinterpret_cast<const bf16x8*>(Bs + (g * 32 + wc * 16 + lr) * 32 + lk * 8);
#pragma unroll
        for (int m = 0; m < 4; ++m)
#pragma unroll
            for (int g = 0; g < 4; ++g)
                acc[m][g] = __builtin_amdgcn_mfma_f32_16x16x32_bf16(af[m], bfr[g], acc[m][g], 0, 0, 0);
        __syncthreads();
    }

    // ---- epilogue: per lane, feature f fixed; all 4 gates local ----
    const int f = f0 + wc * 16 + lr;
    float bs[4];
#pragma unroll
    for (int g = 0; g < 4; ++g) bs[g] = bsum[g * 256 + f];

    int nodev[4][4];
#pragma unroll
    for (int m = 0; m < 4; ++m)
#pragma unroll
        for (int r = 0; r < 4; ++r)
            nodev[m][r] = idx[row0 + wr * 64 + m * 16 + lk * 4 + r];

#pragma unroll
    for (int m = 0; m < 4; ++m) {
#pragma unroll
        for (int r = 0; r < 4; ++r) {
            float gi = acc[m][0][r] + bs[0];
            float gf = acc[m][1][r] + bs[1];
            float gg = acc[m][2][r] + bs[2];
            float go = acc[m][3][r] + bs[3];
            float cp = cell[(size_t)nodev[m][r] * 256 + f];
            float cn = sigmoid_f(gf) * cp + sigmoid_f(gi) * tanh_f(gg);
            float hn = sigmoid_f(go) * tanh_f(cn);
            int row = row0 + wr * 64 + m * 16 + lk * 4 + r;
            h_new[(size_t)row * 256 + f] = f2bf(hn);
        }
    }
}

// ---------------- q GEMM: qbuf = hnew @ WqkT^T + bqk (bf16) ----------------
__global__ __launch_bounds__(256) void k_qk(
    const ushort* __restrict__ hnew, const ushort* __restrict__ WqkT,
    const float* __restrict__ bqk, ushort* __restrict__ qbuf)
{
    __shared__ ushort As[64 * 32];   // 4 KB
    const int t = threadIdx.x, w = t >> 6, l = t & 63;
    const int lr = l & 15, lk = l >> 4;
    const int row0 = blockIdx.x * 64;

    f32x4 acc[4][4];
#pragma unroll
    for (int m = 0; m < 4; ++m)
#pragma unroll
        for (int n = 0; n < 4; ++n) acc[m][n] = f32x4{0.f, 0.f, 0.f, 0.f};

    const int srow = w * 16 + (l >> 2);
    const int scol = (l & 3) * 8;
    const ushort* aS = hnew + (size_t)(row0 + srow) * 256 + scol;
    ushort* aL = As + (w * 16) * 32;

    const ushort* bptr[4];
#pragma unroll
    for (int n = 0; n < 4; ++n) bptr[n] = WqkT + (size_t)(w * 64 + n * 16 + lr) * 256 + lk * 8;

    for (int k0 = 0; k0 < 256; k0 += 32) {
        gload16(aS + k0, aL);
        __syncthreads();
        bf16x8 a[4], b[4];
#pragma unroll
        for (int m = 0; m < 4; ++m)
            a[m] = *reinterpret_cast<const bf16x8*>(As + (m * 16 + lr) * 32 + lk * 8);
#pragma unroll
        for (int n = 0; n < 4; ++n) b[n] = *reinterpret_cast<const bf16x8*>(bptr[n] + k0);
#pragma unroll
        for (int m = 0; m < 4; ++m)
#pragma unroll
            for (int n = 0; n < 4; ++n)
                acc[m][n] = __builtin_amdgcn_mfma_f32_16x16x32_bf16(a[m], b[n], acc[m][n], 0, 0, 0);
        __syncthreads();
    }

#pragma unroll
    for (int m = 0; m < 4; ++m)
#pragma unroll
        for (int n = 0; n < 4; ++n) {
            int colc = w * 64 + n * 16 + lr;
            float bbq = bqk[colc];
#pragma unroll
            for (int r = 0; r < 4; ++r) {
                int row = row0 + m * 16 + lk * 4 + r;
                qbuf[(size_t)row * 256 + colc] = f2bf(acc[m][n][r] + bbq);
            }
        }
}

// ---------------- attention + out GEMM (16 rows/block, grid NB/16) ----------------
static __device__ __forceinline__ int swzb(int row, int byteInRow) {
    return (row * 512 + byteInRow) ^ ((row & 7) << 4);
}

__global__ __launch_bounds__(256) void k_attnout(
    const ushort* __restrict__ qbuf, const ushort* __restrict__ Wvb,
    const float* __restrict__ bv, const int* __restrict__ idx,
    const int* __restrict__ mptr, const float* __restrict__ tm,
    const float* __restrict__ nf, float* __restrict__ out)
{
    __shared__ ushort sC[16 * 256];     // 8 KB: ctx rows (swizzled)
    char* sB = (char*)sC;
    const int t = threadIdx.x, w = t >> 6, l = t & 63;
    const int lr = l & 15, lk = l >> 4;
    const int row0 = blockIdx.x * 16;

    {
        const int b0 = row0 + w * 4;
        int nodes[4], ptrs[4];
#pragma unroll
        for (int r = 0; r < 4; ++r) { nodes[r] = idx[b0 + r]; ptrs[r] = mptr[nodes[r]]; }

#pragma unroll
        for (int rr = 0; rr < 4; ++rr) {
            int row = w * 4 + rr;
            int b = b0 + rr;
            int node = nodes[rr];
            int ptr = ptrs[rr];
            ushort4 q4 = *reinterpret_cast<const ushort4*>(qbuf + (size_t)b * 256 + l * 4);
            float q0 = bf2f(q4.x), q1 = bf2f(q4.y), q2 = bf2f(q4.z), q3 = bf2f(q4.w);
            const float* base = tm + (size_t)node * (NM * NF);

            float4 mem[NM];
            float sc[NM];
#pragma unroll
            for (int m = 0; m < NM; ++m) {
                float4 v;
                if (m == ptr) {
                    v = *reinterpret_cast<const float4*>(nf + (size_t)b * 256 + l * 4);
                } else {
                    v = *reinterpret_cast<const float4*>(base + (size_t)m * 256 + l * 4);
                    if (ptr > 0 && m == ptr - 1) { v.x *= DECAY; v.y *= DECAY; v.z *= DECAY; v.w *= DECAY; }
                }
                mem[m] = v;
                sc[m] = q0 * v.x + q1 * v.y + q2 * v.z + q3 * v.w;
            }
#pragma unroll
            for (int m = 0; m < NM; ++m) {
                float s = sc[m];
#pragma unroll
                for (int d = 1; d < 64; d <<= 1) s += __shfl_xor(s, d, 64);
                sc[m] = s;
            }
            float mx = sc[0];
#pragma unroll
            for (int m = 1; m < NM; ++m) mx = fmaxf(mx, sc[m]);
            float e[NM], sum = 0.f;
#pragma unroll
            for (int m = 0; m < NM; ++m) { e[m] = __expf(sc[m] - mx); sum += e[m]; }
            float inv = 1.f / sum;

            float4 c = {0.f, 0.f, 0.f, 0.f};
#pragma unroll
            for (int m = 0; m < NM; ++m) {
                float wm = e[m] * inv;
                c.x += wm * mem[m].x; c.y += wm * mem[m].y; c.z += wm * mem[m].z; c.w += wm * mem[m].w;
            }
            ushort4 o;
            o.x = f2bf(c.x); o.y = f2bf(c.y); o.z = f2bf(c.z); o.w = f2bf(c.w);
            *(ushort4*)(sB + swzb(row, l * 8)) = o;
        }
    }
    __syncthreads();

    f32x4 acc[4];
#pragma unroll
    for (int n = 0; n < 4; ++n) acc[n] = f32x4{0.f, 0.f, 0.f, 0.f};
    const ushort* vptr[4];
#pragma unroll
    for (int n = 0; n < 4; ++n) vptr[n] = Wvb + (size_t)(w * 64 + n * 16 + lr) * 256 + lk * 8;

#pragma unroll 2
    for (int k = 0; k < 256; k += 32) {
        bf16x8 a = *reinterpret_cast<const bf16x8*>(sB + swzb(lr, (k + lk * 8) * 2));
        bf16x8 b[4];
#pragma unroll
        for (int n = 0; n < 4; ++n) b[n] = *reinterpret_cast<const bf16x8*>(vptr[n] + k);
#pragma unroll
        for (int n = 0; n < 4; ++n)
            acc[n] = __builtin_amdgcn_mfma_f32_16x16x32_bf16(a, b[n], acc[n], 0, 0, 0);
    }
#pragma unroll
    for (int n = 0; n < 4; ++n) {
        int colc = w * 64 + n * 16 + lr;
        float bbv = bv[colc];
#pragma unroll
        for (int r = 0; r < 4; ++r) {
            int row = lk * 4 + r;
            out[(size_t)(row0 + row) * 256 + colc] = acc[n][r] + bbv;
        }
    }
}

// ---------------- launch ----------------
extern "C" void kernel_launch(void* const* d_in, const int* in_sizes, int n_in,
                              void* d_out, int out_size, void* d_ws, size_t ws_size,
                              hipStream_t stream) {
    const int*   node_indices = (const int*)  d_in[0];
    const float* node_feats   = (const float*)d_in[1];
    const float* hidden       = (const float*)d_in[2];
    const float* cell         = (const float*)d_in[3];
    const float* tmem         = (const float*)d_in[4];
    const int*   memory_ptr   = (const int*)  d_in[5];
    const float* W_ih         = (const float*)d_in[6];
    const float* W_hh         = (const float*)d_in[7];
    const float* b_ih         = (const float*)d_in[8];
    const float* b_hh         = (const float*)d_in[9];
    const float* Wq           = (const float*)d_in[10];
    const float* bq           = (const float*)d_in[11];
    const float* Wk           = (const float*)d_in[12];
    // d_in[13] = bk: softmax-invariant, unused
    const float* Wv           = (const float*)d_in[14];
    const float* bv           = (const float*)d_in[15];

    char* ws = (char*)d_ws;
    size_t off = 0;
    auto alloc = [&](size_t bytes) { char* p = ws + off; off += (bytes + 255) & ~(size_t)255; return p; };

    ushort* Wg    = (ushort*)alloc((size_t)1024 * 512 * 2);
    ushort* WqkT  = (ushort*)alloc((size_t)256 * 256 * 2);
    ushort* Wvb   = (ushort*)alloc((size_t)256 * 256 * 2);
    float*  bqk   = (float*) alloc((size_t)256 * 4);
    float*  bsum  = (float*) alloc((size_t)1024 * 4);
    ushort* Acat  = (ushort*)alloc((size_t)NB * 512 * 2);
    ushort* hnew  = (ushort*)alloc((size_t)NB * 256 * 2);
    ushort* qbuf  = (ushort*)alloc((size_t)NB * 256 * 2);

    k_prep<<<PB_TOT, 256, 0, stream>>>(W_ih, W_hh, b_ih, b_hh, Wq, bq, Wk, Wv,
                                       node_feats, hidden, node_indices,
                                       Wg, bsum, WqkT, bqk, Wvb, Acat);
    k_gates2<<<2048, 256, 0, stream>>>(Acat, Wg, bsum, node_indices, cell, hnew);
    k_qk<<<NB / 64, 256, 0, stream>>>(hnew, WqkT, bqk, qbuf);
    k_attnout<<<NB / 16, 256, 0, stream>>>(qbuf, Wvb, bv, node_indices, memory_ptr,
                                           tmem, node_feats, (float*)d_out);
}